// Round 10
// baseline (403.534 us; speedup 1.0000x reference)
//
#include <hip/hip_runtime.h>
#include <math.h>

// Problem constants
#define B_   2
#define T_   2048
#define D_   1024
#define C_   10
#define F_   513
#define NTOK (B_ * T_)     // 4096 rows
#define LF   3078          // Fall stride: [q interleaved(1026) | k(1026) | v(1026)]
#define KP2  1056          // padded K for output GEMM (cols 0..1025 used, pad 30)
#define NCH  128           // scan chunks
#define TC   (T_ / NCH)    // 16 timesteps per chunk

typedef unsigned short us16;
typedef __attribute__((ext_vector_type(8))) __bf16 bf16x8;
typedef __attribute__((ext_vector_type(4))) float  f32x4;

// Workspace layout (bytes) — R9's layout. RCAT aliases PREP (WT+WoBf+Tcs,
// 10.49 MB >= 8.65 MB needed; all builders finish before scan_apply writes).
#define O_XBF    ((size_t)0)                 // x bf16: 8,388,608
#define O_PREP   ((size_t)8388608)
#define O_WT     (O_PREP)                    // WT bf16 3x1024x1024: 6,291,456
#define O_WOBF   (O_PREP + 6291456)          // Wo bf16: 2,097,152
#define O_TCS    (O_PREP + 8388608)          // Tcs bf16 1026x1024: 2,101,248
#define O_RCAT   (O_PREP)                    // Rcat bf16 4096x1056: 8,650,752
#define O_SFB    (O_PREP + 10489856)         // Sfb bf16 1056x1024: 2,162,688
#define O_MALLB  (O_SFB + 2162688)           // Mall bf16 3x1026x1024: 6,303,744
#define O_MOUTB  (O_MALLB + 6303744)         // MoutT bf16 1024x1056: 2,162,688
#define O_FALL   (O_MOUTB + 2162688)         // Fall fp32 4096x3078: 50,429,952
#define O_SSCAN  (O_FALL + 50429952)         // scan sums fp32: 10,506,240

__device__ __forceinline__ us16 f2b(float f) {
    union { float f; unsigned u; } v; v.f = f;
    unsigned r = v.u + 0x7FFFu + ((v.u >> 16) & 1u);
    return (us16)(r >> 16);
}

// ---------------------------------------------------------------------------
// float -> bf16 copy-convert (vectorized by 4)
// ---------------------------------------------------------------------------
__global__ void hrr_cvt_bf16(const float* __restrict__ in, us16* __restrict__ out, int n4) {
    int i = blockIdx.x * 256 + threadIdx.x;
    if (i < n4) {
        float4 v = ((const float4*)in)[i];
        ushort4 o;
        o.x = f2b(v.x); o.y = f2b(v.y); o.z = f2b(v.z); o.w = f2b(v.w);
        ((ushort4*)out)[i] = o;
    }
}

// ---------------------------------------------------------------------------
// Transpose W (1024x1024 fp32) -> bf16, 3 matrices via blockIdx.z
// ---------------------------------------------------------------------------
__global__ void hrr_transpose_bf16(const float* __restrict__ Wq,
                                   const float* __restrict__ Wk,
                                   const float* __restrict__ Wv,
                                   us16* __restrict__ WT) {
    const float* W = (blockIdx.z == 0) ? Wq : (blockIdx.z == 1) ? Wk : Wv;
    us16* O = WT + (size_t)blockIdx.z * D_ * D_;
    __shared__ float t[32][33];
    const int bx = blockIdx.x * 32, by = blockIdx.y * 32;
    const int tx = threadIdx.x & 31, ty = threadIdx.x >> 5;   // 32 x 8
#pragma unroll
    for (int i = 0; i < 32; i += 8)
        t[ty + i][tx] = W[(size_t)(by + ty + i) * D_ + bx + tx];
    __syncthreads();
#pragma unroll
    for (int i = 0; i < 32; i += 8)
        O[(size_t)(bx + ty + i) * D_ + by + tx] = f2b(t[tx][ty + i]);
}

// ---------------------------------------------------------------------------
// Trig builder: each thread computes ONE (f,e) cos/sin pair and writes both
// Tcs (interleaved rows 2f=cos, 2f+1=-sin) and Sfb (same, scaled by s_f).
// Tail blocks zero Sfb pad rows 1026..1055.
// ---------------------------------------------------------------------------
#define NTRIG (513 * 1024)
__global__ void hrr_build_trig2(us16* __restrict__ Tcs, us16* __restrict__ Sfb) {
    int idx = blockIdx.x * 256 + threadIdx.x;
    if (idx < NTRIG) {
        int f = idx >> 10, e = idx & 1023;
        float ang = (float)((f * e) & 1023) * 6.135923151542565e-3f;  // 2*pi/1024
        float cs = cosf(ang), sn = -sinf(ang);
        float s = (f == 0 || f == 512) ? (1.0f / 1024.0f) : (2.0f / 1024.0f);
        size_t o = ((size_t)(2 * f) << 10) + e;
        Tcs[o]        = f2b(cs);
        Tcs[o + 1024] = f2b(sn);
        Sfb[o]        = f2b(s * cs);
        Sfb[o + 1024] = f2b(s * sn);
    } else {
        int j = idx - NTRIG;                         // Sfb pad rows 1026..1055
        if (j < 30 * 1024) Sfb[(size_t)1026 * 1024 + j] = 0;
    }
}

// ---------------------------------------------------------------------------
// GEMM core (R9 engine, TM-parameterized): C(MxN) = A(MxK) @ B(NxK)^T.
// TM x 128 tile, 256 threads (2x2 waves), K-step 32, 16x16x32 MFMA, register
// prefetch of tile k+1. K mult 32, lda/ldb mult 8. Staging clamps, epilogue
// guards M/N edges.
// ---------------------------------------------------------------------------
template <bool OUT_BF16, int TM>
__device__ __forceinline__ void gemm_core(const us16* __restrict__ A,
                                          const us16* __restrict__ B,
                                          void* __restrict__ Cv,
                                          int M, int N, int K,
                                          int lda, int ldb, int ldc,
                                          int bm, int bn) {
    constexpr int NA = TM / 64;       // A staging granules (64 rows each)
    constexpr int WM = TM / 2;        // wave M-tile
    constexpr int MI = WM / 16;       // A fragments per wave

    __shared__ us16 As[TM * 32];
    __shared__ us16 Bs[128 * 32];

    const int tid  = threadIdx.x;
    const int lane = tid & 63;
    const int wave = tid >> 6;
    const int wm = (wave >> 1) * WM;
    const int wn = (wave & 1) * 64;

    const int r0 = tid >> 2;          // 0..63 staging row
    const int c4 = (tid & 3) * 8;     // k-offset (elements)

    const us16* pA[NA];
#pragma unroll
    for (int g = 0; g < NA; g++) {
        int r = bm + g * 64 + r0; if (r >= M) r = M - 1;
        pA[g] = A + (size_t)r * lda + c4;
    }
    const us16* pB[2];
#pragma unroll
    for (int g = 0; g < 2; g++) {
        int r = bn + g * 64 + r0; if (r >= N) r = N - 1;
        pB[g] = B + (size_t)r * ldb + c4;
    }

    f32x4 acc[MI][4];
#pragma unroll
    for (int i = 0; i < MI; i++)
#pragma unroll
        for (int j = 0; j < 4; j++) acc[i][j] = (f32x4){0.f, 0.f, 0.f, 0.f};

    const int fr = lane & 15;
    const int kg = (lane >> 4) * 8;

    uint4 aR[NA], bR[2];
#pragma unroll
    for (int g = 0; g < NA; g++) aR[g] = *(const uint4*)(pA[g]);
#pragma unroll
    for (int g = 0; g < 2; g++)  bR[g] = *(const uint4*)(pB[g]);

    for (int k0 = 0; k0 < K; k0 += 32) {
        __syncthreads();
#pragma unroll
        for (int g = 0; g < NA; g++)
            *(uint4*)(As + (g * 64 + r0) * 32 + c4) = aR[g];
#pragma unroll
        for (int g = 0; g < 2; g++)
            *(uint4*)(Bs + (g * 64 + r0) * 32 + c4) = bR[g];
        __syncthreads();

        const int kn = k0 + 32;
        if (kn < K) {                               // prefetch next tile
#pragma unroll
            for (int g = 0; g < NA; g++) aR[g] = *(const uint4*)(pA[g] + kn);
#pragma unroll
            for (int g = 0; g < 2; g++)  bR[g] = *(const uint4*)(pB[g] + kn);
        }

        bf16x8 af[MI], bfr[4];
#pragma unroll
        for (int i = 0; i < MI; i++)
            af[i] = *(const bf16x8*)(As + (wm + i * 16 + fr) * 32 + kg);
#pragma unroll
        for (int j = 0; j < 4; j++)
            bfr[j] = *(const bf16x8*)(Bs + (wn + j * 16 + fr) * 32 + kg);
#pragma unroll
        for (int i = 0; i < MI; i++)
#pragma unroll
            for (int j = 0; j < 4; j++)
                acc[i][j] = __builtin_amdgcn_mfma_f32_16x16x32_bf16(af[i], bfr[j], acc[i][j], 0, 0, 0);
    }

    // epilogue: C/D layout col=lane&15, row=(lane>>4)*4+reg
    const int cl = lane & 15;
    const int rq = (lane >> 4) * 4;
#pragma unroll
    for (int i = 0; i < MI; i++) {
#pragma unroll
        for (int j = 0; j < 4; j++) {
#pragma unroll
            for (int r = 0; r < 4; r++) {
                int row = bm + wm + i * 16 + rq + r;
                int col = bn + wn + j * 16 + cl;
                if (row < M && col < N) {
                    size_t o = (size_t)row * ldc + col;
                    if (OUT_BF16) ((us16*)Cv)[o] = f2b(acc[i][j][r]);
                    else          ((float*)Cv)[o] = acc[i][j][r];
                }
            }
        }
    }
}

// ---------------------------------------------------------------------------
// Plain GEMM kernel wrapper (main GEMM TM=128, output GEMM TM=64)
// ---------------------------------------------------------------------------
template <bool OUT_BF16, int TM>
__global__ __launch_bounds__(256, 3)
void hrr_gemm_tm(const us16* __restrict__ A, const us16* __restrict__ B,
                 void* __restrict__ C, int M, int N, int K,
                 int lda, int ldb, int ldc) {
    gemm_core<OUT_BF16, TM>(A, B, C, M, N, K, lda, ldb, ldc,
                            blockIdx.y * TM, blockIdx.x * 128);
}

// ---------------------------------------------------------------------------
// Merged builders: one launch does both builder GEMMs at TM=64 for occupancy.
//   z<3 : Mall_z(1026x1024) = Tcs @ WT_z^T      (grid slice 8 x 17)
//   z==3: MoutT(1024x1056)  = WoBf @ Sfb^T      (grid slice 9 x 16)
// Grid (9, 17, 4); inactive blocks exit before any barrier.
// ---------------------------------------------------------------------------
__global__ __launch_bounds__(256, 3)
void hrr_gemm_builders(const us16* __restrict__ Tcs, const us16* __restrict__ WT,
                       us16* __restrict__ MallB,
                       const us16* __restrict__ WoBf, const us16* __restrict__ Sfb,
                       us16* __restrict__ MoutB) {
    const int z = blockIdx.z;
    const us16 *A, *B; us16* C;
    int M, N, ldc;
    if (z < 3) {
        if (blockIdx.x >= 8) return;
        A = Tcs; B = WT + (size_t)z * D_ * D_; C = MallB + (size_t)z * 1026 * 1024;
        M = 1026; N = 1024; ldc = 1024;
    } else {
        if (blockIdx.y >= 16) return;
        A = WoBf; B = Sfb; C = MoutB;
        M = 1024; N = KP2; ldc = KP2;
    }
    gemm_core<true, 64>(A, B, C, M, N, 1024, 1024, 1024, ldc,
                        blockIdx.y * 64, blockIdx.x * 128);
}

// ---------------------------------------------------------------------------
// Scan phase 1: chunk sums. Grid (NCH, B_, 2) f-halves, 256 threads.
// Interleaved complex: one float2 LDS gather per c instead of two b32.
// z=0 owns f=tid; z=1 owns f=256+tid plus f=512 on thread 0.
// ---------------------------------------------------------------------------
__global__ __launch_bounds__(256, 4)
void hrr_scan_sums(const float* __restrict__ Fall, const int* __restrict__ perms,
                   float* __restrict__ S) {
    const int n = blockIdx.x, b = blockIdx.y, half = blockIdx.z;
    const int tid = threadIdx.x;
    const int f0 = half * 256;
    const int VL = half ? 257 : 256;
    __shared__ float2 kc[F_], vc[257];

    float aR[2][C_], aI[2][C_];
    int gg[2][C_];
#pragma unroll
    for (int i = 0; i < 2; i++) {
        const int f = (i == 0) ? (f0 + tid) : 512;
        const bool act = (i == 0) || (half == 1 && tid == 0);
#pragma unroll
        for (int c = 0; c < C_; c++) {
            gg[i][c] = act ? perms[c * F_ + f] : 0;
            aR[i][c] = aI[i][c] = 0.f;
        }
    }

    for (int tl = 0; tl < TC; tl++) {
        const float* row = Fall + (size_t)(b * T_ + n * TC + tl) * LF;
        __syncthreads();
        for (int j = tid; j < F_; j += 256)
            kc[j] = *(const float2*)(row + 1026 + 2 * j);
        for (int j = tid; j < VL; j += 256)
            vc[j] = *(const float2*)(row + 2052 + 2 * (f0 + j));
        __syncthreads();
#pragma unroll
        for (int i = 0; i < 2; i++) {
            const int lv = (i == 0) ? tid : 256;
            if (i == 0 || (half == 1 && tid == 0)) {
                float2 v = vc[lv];
#pragma unroll
                for (int c = 0; c < C_; c++) {
                    float2 k = kc[gg[i][c]];
                    aR[i][c] += k.x * v.x - k.y * v.y;
                    aI[i][c] += k.x * v.y + k.y * v.x;
                }
            }
        }
    }
#pragma unroll
    for (int i = 0; i < 2; i++) {
        const int f = (i == 0) ? (f0 + tid) : 512;
        if (i == 0 || (half == 1 && tid == 0)) {
#pragma unroll
            for (int c = 0; c < C_; c++) {
                size_t a = ((((size_t)c * B_ + b) * NCH + n) * F_ + f) * 2;
                S[a] = aR[i][c]; S[a + 1] = aI[i][c];
            }
        }
    }
}

// ---------------------------------------------------------------------------
// Scan phase 2: exclusive prefix over chunks, per (c,b,f). 8-way unrolled.
// ---------------------------------------------------------------------------
__global__ void hrr_scan_prefix(float* __restrict__ S) {
    int tid = blockIdx.x * 256 + threadIdx.x;
    if (tid >= C_ * B_ * F_) return;
    int c = tid / (B_ * F_);
    int r = tid % (B_ * F_);
    int b = r / F_, f = r % F_;
    size_t base = (((size_t)c * B_ + b) * NCH) * F_ + f;
    float runR = 0.f, runI = 0.f;
    for (int n0 = 0; n0 < NCH; n0 += 8) {
        float tR[8], tI[8];
#pragma unroll
        for (int u = 0; u < 8; u++) {
            size_t a = (base + (size_t)(n0 + u) * F_) * 2;
            tR[u] = S[a]; tI[u] = S[a + 1];
        }
#pragma unroll
        for (int u = 0; u < 8; u++) {
            size_t a = (base + (size_t)(n0 + u) * F_) * 2;
            S[a] = runR; S[a + 1] = runI;
            runR += tR[u]; runI += tI[u];
        }
    }
}

// ---------------------------------------------------------------------------
// Scan phase 3: running kv in regs, r = mean_c kv*conj(fqp) -> Rcat (bf16,
// interleaved cols 2f/2f+1, one packed u32 store). Grid (NCH, B_, 2).
// half==0 blocks zero the 30 pad columns.
// ---------------------------------------------------------------------------
__global__ __launch_bounds__(256, 4)
void hrr_scan_apply(const float* __restrict__ Fall, const int* __restrict__ perms,
                    const float* __restrict__ S, us16* __restrict__ Rcat) {
    const int n = blockIdx.x, b = blockIdx.y, half = blockIdx.z;
    const int tid = threadIdx.x;
    const int f0 = half * 256;
    const int VL = half ? 257 : 256;
    __shared__ float2 qc[F_], kc[F_], vc[257];

    float kvR[2][C_], kvI[2][C_];
    int gg[2][C_];
#pragma unroll
    for (int i = 0; i < 2; i++) {
        const int f = (i == 0) ? (f0 + tid) : 512;
        const bool act = (i == 0) || (half == 1 && tid == 0);
#pragma unroll
        for (int c = 0; c < C_; c++) {
            gg[i][c] = act ? perms[c * F_ + f] : 0;
            if (act) {
                size_t a = ((((size_t)c * B_ + b) * NCH + n) * F_ + f) * 2;
                kvR[i][c] = S[a]; kvI[i][c] = S[a + 1];
            } else { kvR[i][c] = 0.f; kvI[i][c] = 0.f; }
        }
    }

    for (int tl = 0; tl < TC; tl++) {
        const int tt = b * T_ + n * TC + tl;
        const float* row = Fall + (size_t)tt * LF;
        __syncthreads();
        for (int j = tid; j < F_; j += 256) {
            qc[j] = *(const float2*)(row + 2 * j);
            kc[j] = *(const float2*)(row + 1026 + 2 * j);
        }
        for (int j = tid; j < VL; j += 256)
            vc[j] = *(const float2*)(row + 2052 + 2 * (f0 + j));
        __syncthreads();
        unsigned* out32 = (unsigned*)(Rcat + (size_t)tt * KP2);
#pragma unroll
        for (int i = 0; i < 2; i++) {
            const int f = (i == 0) ? (f0 + tid) : 512;
            const int lv = (i == 0) ? tid : 256;
            if (i == 0 || (half == 1 && tid == 0)) {
                float2 v = vc[lv];
                float accR = 0.f, accI = 0.f;
#pragma unroll
                for (int c = 0; c < C_; c++) {
                    int g = gg[i][c];
                    float2 k = kc[g];
                    float nR = kvR[i][c] + k.x * v.x - k.y * v.y;
                    float nI = kvI[i][c] + k.x * v.y + k.y * v.x;
                    kvR[i][c] = nR; kvI[i][c] = nI;
                    float2 q = qc[g];
                    accR += nR * q.x + nI * q.y;
                    accI += nI * q.x - nR * q.y;
                }
                out32[f] = (unsigned)f2b(accR * 0.1f)
                         | ((unsigned)f2b(accI * 0.1f) << 16);
            }
        }
        if (half == 0 && tid < 15)                  // zero pad cols 1026..1055
            out32[513 + tid] = 0;
    }
}

// ---------------------------------------------------------------------------
extern "C" void kernel_launch(void* const* d_in, const int* in_sizes, int n_in,
                              void* d_out, int out_size, void* d_ws, size_t ws_size,
                              hipStream_t stream) {
    const float* x  = (const float*)d_in[0];
    const float* Wq = (const float*)d_in[1];
    const float* Wk = (const float*)d_in[2];
    const float* Wv = (const float*)d_in[3];
    const float* Wo = (const float*)d_in[4];
    const int* perms = (const int*)d_in[5];
    float* out = (float*)d_out;

    char* ws = (char*)d_ws;
    us16* Xbf   = (us16*)(ws + O_XBF);
    us16* WT    = (us16*)(ws + O_WT);
    us16* WoBf  = (us16*)(ws + O_WOBF);
    us16* Tcs   = (us16*)(ws + O_TCS);
    us16* Sfb   = (us16*)(ws + O_SFB);
    us16* MallB = (us16*)(ws + O_MALLB);
    us16* MoutB = (us16*)(ws + O_MOUTB);
    us16* Rcat  = (us16*)(ws + O_RCAT);
    float* Fall = (float*)(ws + O_FALL);
    float* Ssc  = (float*)(ws + O_SSCAN);

    // prep (separate small kernels — mega-prep fusion proven harmful in R7/R8)
    hrr_cvt_bf16<<<4096, 256, 0, stream>>>(x, Xbf, NTOK * D_ / 4);
    hrr_cvt_bf16<<<1024, 256, 0, stream>>>(Wo, WoBf, D_ * D_ / 4);
    hrr_transpose_bf16<<<dim3(32, 32, 3), 256, 0, stream>>>(Wq, Wk, Wv, WT);
    hrr_build_trig2<<<(NTRIG + 30 * 1024 + 255) / 256, 256, 0, stream>>>(Tcs, Sfb);

    // merged builders: Mall (3 batches) + MoutT in ONE launch, TM=64
    hrr_gemm_builders<<<dim3(9, 17, 4), 256, 0, stream>>>(
        Tcs, WT, MallB, WoBf, Sfb, MoutB);

    // main GEMM: Fall(4096x3078 fp32) = Xbf @ MallB^T  (TM=128, R9-identical)
    hrr_gemm_tm<false, 128><<<dim3(25, 32), 256, 0, stream>>>(
        Xbf, MallB, Fall, NTOK, LF, 1024, 1024, 1024, LF);

    // chunked causal scan (scan_apply zeroes Rcat pad columns itself)
    hrr_scan_sums<<<dim3(NCH, B_, 2), 256, 0, stream>>>(Fall, perms, Ssc);
    hrr_scan_prefix<<<(C_ * B_ * F_ + 255) / 256, 256, 0, stream>>>(Ssc);
    hrr_scan_apply<<<dim3(NCH, B_, 2), 256, 0, stream>>>(Fall, perms, Ssc, Rcat);

    // output GEMM: out(4096x1024 fp32) = Rcat @ MoutB^T, TM=64 (512 blocks)
    hrr_gemm_tm<false, 64><<<dim3(8, 64), 256, 0, stream>>>(
        Rcat, MoutB, out, NTOK, D_, KP2, KP2, KP2, D_);
}